// Round 18
// baseline (691.479 us; speedup 1.0000x reference)
//
#include <hip/hip_runtime.h>

#define HID 256
#define NSEQ 1024
#define NH 16
#define DH 4
#define NB 4
#define SCALEF 0.5f
#define HEADSZ (NB * NH * NSEQ * DH)   // 262144 floats per projection buffer
#define CNT_OFF (4u * 1024u * 1024u)   // counters at ws + 4MB (past proj/x2)

typedef float f4 __attribute__((ext_vector_type(4)));

__device__ __forceinline__ float rfl(float x) {
    return __builtin_bit_cast(float,
        __builtin_amdgcn_readfirstlane(__builtin_bit_cast(int, x)));
}

#define LOG2E 1.44269504f
#define EOFF  (-16.f * LOG2E)

// ---------------------------------------------------------------------------
// ONE normal launch, three phases, software grid barrier.
// Residency-safe: 256 blocks x 1024 thr, 64KB LDS -> capacity 2 blocks/CU,
// 512 slots >= 256 blocks -> every block is placed immediately, spin cannot
// deadlock. (R14's coop path capped residency at 2/CU as a RUNTIME policy;
// a normal launch has no such cap -> 16 waves/CU during attn, same as R17.)
// P1: proj on blocks 0-47 (4x256-thread sub-units each).  barrier(48)
// P2: attn; block = (b,h, 4 segs) -> K/V staged ONCE (8MB total staging).
// P3: out-proj+BN+LeakyReLU, 1 f4/thread.               barrier(256)
// Counters zeroed per call by hipMemsetAsync (graph-capture-legal).
// ---------------------------------------------------------------------------
__global__ __launch_bounds__(1024, 4) void fused_kernel(
    const float* __restrict__ q, const float* __restrict__ k,
    const float* __restrict__ v, const float* __restrict__ bias,
    const float* __restrict__ Wq, const float* __restrict__ Wk,
    const float* __restrict__ Wv, const float* __restrict__ Wo,
    const float* __restrict__ bo, const float* __restrict__ gamma,
    const float* __restrict__ beta, const float* __restrict__ rmean,
    const float* __restrict__ rvar, float* ws, float* out)
{
    __shared__ float smem[16384];              // 64 KB, reused per phase
    const int tid = threadIdx.x;
    const int blk = blockIdx.x;
    unsigned* counters = (unsigned*)((char*)ws + CNT_OFF);
    float* x2 = ws + (size_t)3 * HEADSZ;

    // ---------------- P1: projections (blocks 0..47) ----------------
    if (blk < 48) {
        const int s    = tid >> 8;             // sub-unit 0..3
        const int stid = tid & 255;
        const int unit = blk * 4 + s;          // 192 proj units
        const int pos0 = (unit & 15) * 64;
        const int p    = (unit >> 4) % 3;
        const int b    = unit / 48;
        const float* in = (p == 0) ? q : (p == 1) ? k : v;
        const float* W  = (p == 0) ? Wq : (p == 1) ? Wk : Wv;
        float* dst = ws + (size_t)p * HEADSZ;

        float (*lds_in)[64] = (float(*)[64])(smem + s * 4096);  // 16KB each
        const int pos_l = stid & 63;
        int cb = __builtin_amdgcn_readfirstlane(stid >> 6);
        const int row_l = stid >> 4;
        const int col4  = stid & 15;
        const float* inb = in + (size_t)b * HID * NSEQ + pos0;

        float acc[16];
#pragma unroll
        for (int j = 0; j < 16; ++j) acc[j] = 0.f;

        f4 vbuf[4];
#pragma unroll
        for (int t = 0; t < 4; ++t)
            vbuf[t] = *(const f4*)(inb + (size_t)(row_l + 16 * t) * NSEQ + col4 * 4);

        for (int c = 0; c < 4; ++c) {
#pragma unroll
            for (int t = 0; t < 4; ++t)
                *(f4*)&lds_in[row_l + 16 * t][col4 * 4] = vbuf[t];
            __syncthreads();
            if (c < 3) {
#pragma unroll
                for (int t = 0; t < 4; ++t)
                    vbuf[t] = *(const f4*)(inb +
                        (size_t)((c + 1) * 64 + row_l + 16 * t) * NSEQ + col4 * 4);
            }
#pragma unroll
            for (int i8 = 0; i8 < 64; i8 += 8) {
                float x[8];
#pragma unroll
                for (int j = 0; j < 8; ++j) x[j] = lds_in[i8 + j][pos_l];
#pragma unroll
                for (int kk = 0; kk < 16; ++kk) {
                    const float* wr = W + (cb * 16 + kk) * HID + c * 64 + i8;
#pragma unroll
                    for (int j = 0; j < 8; ++j)
                        acc[kk] = fmaf(wr[j], x[j], acc[kk]);
                }
            }
            __syncthreads();
        }

        const int pos_g = pos0 + pos_l;
        const int hh    = pos_g & 15;
        const int nsub  = pos_g >> 4;
#pragma unroll
        for (int kk = 0; kk < 16; ++kk) {
            int c = cb * 16 + kk;
            int d = c >> 4;
            int n = (c & 15) * 64 + nsub;
            dst[(((size_t)b * NH + hh) * NSEQ + n) * DH + d] = acc[kk];
        }
    }

    // ---------------- barrier 1: proj visible to all ----------------
    __threadfence();
    __syncthreads();
    if (blk < 48 && tid == 0)
        __hip_atomic_fetch_add(&counters[0], 1u, __ATOMIC_RELEASE,
                               __HIP_MEMORY_SCOPE_AGENT);
    if (tid == 0) {
        while (__hip_atomic_load(&counters[0], __ATOMIC_ACQUIRE,
                                 __HIP_MEMORY_SCOPE_AGENT) < 48u)
            __builtin_amdgcn_s_sleep(8);
    }
    __syncthreads();
    __threadfence();

    // ---------------- P2: attention ----------------
    {
        const int lane = tid & 63;
        const int wave = tid >> 6;             // 0..15
        const int b    = blk >> 6;
        const int h    = (blk >> 2) & 15;
        const int headbase = (b * NH + h) * NSEQ;
        const int mb = lane * 4;

        const float4* Qh = (const float4*)(ws);
        const float4* Kh = (const float4*)(ws + (size_t)1 * HEADSZ);
        const float4* Vh = (const float4*)(ws + (size_t)2 * HEADSZ);

        float4* ldsK = (float4*)smem;          // 16 KB
        float4* ldsV = ldsK + NSEQ;            // 16 KB

        // stage this block's head ONCE (all 4 segments share it)
        ldsK[tid] = Kh[headbase + tid];
        ldsV[tid] = Vh[headbase + tid];
        __syncthreads();

#pragma unroll 1
        for (int u4 = 0; u4 < 4; ++u4) {
            const int seg = (blk & 3) * 4 + u4;
            const int n0  = seg * 64 + wave * 4;   // wave's 4 rows

            float qx[4], qy[4], qz[4], qw[4];
#pragma unroll
            for (int r = 0; r < 4; ++r) {
                float4 t = Qh[headbase + n0 + r];
                qx[r] = rfl(t.x); qy[r] = rfl(t.y);
                qz[r] = rfl(t.z); qw[r] = rfl(t.w);
            }

            float sum[4];
            float o[4][4];
#pragma unroll
            for (int r = 0; r < 4; ++r) {
                sum[r] = 0.f;
                o[r][0] = o[r][1] = o[r][2] = o[r][3] = 0.f;
            }

            const float* bwave = bias + ((size_t)headbase + n0) * NSEQ + mb;

#pragma unroll 1
            for (int c = 0; c < 4; ++c) {
                float4 kb[4], vb[4];
#pragma unroll
                for (int i = 0; i < 4; ++i) {
                    kb[i] = ldsK[c * 256 + mb + i];
                    vb[i] = ldsV[c * 256 + mb + i];
                }
#pragma unroll
                for (int r = 0; r < 4; ++r) {
                    f4 bb = *(const f4*)(bwave + (size_t)r * NSEQ + c * 256);
#pragma unroll
                    for (int i = 0; i < 4; ++i) {
                        float dot = qx[r] * kb[i].x + qy[r] * kb[i].y +
                                    qz[r] * kb[i].z + qw[r] * kb[i].w;
                        float s = fmaf(dot, SCALEF, bb[i]);
                        float e = exp2f(fmaf(s, LOG2E, EOFF));   // exp(s-16)
                        sum[r] += e;
                        o[r][0] = fmaf(e, vb[i].x, o[r][0]);
                        o[r][1] = fmaf(e, vb[i].y, o[r][1]);
                        o[r][2] = fmaf(e, vb[i].z, o[r][2]);
                        o[r][3] = fmaf(e, vb[i].w, o[r][3]);
                    }
                }
            }

#pragma unroll
            for (int r = 0; r < 4; ++r) {
                float s = sum[r], a0 = o[r][0], a1 = o[r][1],
                      a2 = o[r][2], a3 = o[r][3];
#pragma unroll
                for (int st = 1; st < 64; st <<= 1) {
                    s  += __shfl_xor(s,  st, 64);
                    a0 += __shfl_xor(a0, st, 64);
                    a1 += __shfl_xor(a1, st, 64);
                    a2 += __shfl_xor(a2, st, 64);
                    a3 += __shfl_xor(a3, st, 64);
                }
                float val = (lane == 0) ? a0 : (lane == 1) ? a1
                          : (lane == 2) ? a2 : a3;
                if (lane < 4)
                    x2[((size_t)b * (NH * DH) + h * DH + lane) * NSEQ + n0 + r] =
                        val / s;
            }
        }
    }

    // ---------------- barrier 2: x2 visible to all ----------------
    __threadfence();
    __syncthreads();
    if (tid == 0)
        __hip_atomic_fetch_add(&counters[1], 1u, __ATOMIC_RELEASE,
                               __HIP_MEMORY_SCOPE_AGENT);
    if (tid == 0) {
        while (__hip_atomic_load(&counters[1], __ATOMIC_ACQUIRE,
                                 __HIP_MEMORY_SCOPE_AGENT) < 256u)
            __builtin_amdgcn_s_sleep(8);
    }
    __syncthreads();
    __threadfence();

    // ---------------- P3: out-proj + BN + LeakyReLU ----------------
    {
        const int g    = blk * 1024 + tid;     // 262144 f4-units
        const int b    = g >> 16;
        const int oc   = (g >> 8) & 255;       // wave-uniform -> scalar Wo
        const int pos4 = (g & 255) * 4;

        const float* xb = x2 + (size_t)b * (NH * DH) * NSEQ;
        f4 acc = (f4)(0.f);
#pragma unroll 16
        for (int c = 0; c < NH * DH; ++c) {
            f4 x = *(const f4*)(xb + (size_t)c * NSEQ + pos4);
            acc += Wo[oc * (NH * DH) + c] * x;
        }
        float scale = gamma[oc] * rsqrtf(rvar[oc] + 1e-5f);
        f4 y = (acc + (bo[oc] - rmean[oc])) * scale + beta[oc];
        f4 res;
#pragma unroll
        for (int d = 0; d < 4; ++d) {
            float yy = y[d];
            res[d] = (yy > 0.f) ? yy : 0.2f * yy;
        }
        *(f4*)(out + ((size_t)b * HID + oc) * NSEQ + pos4) = res;
    }
}

extern "C" void kernel_launch(void* const* d_in, const int* in_sizes, int n_in,
                              void* d_out, int out_size, void* d_ws, size_t ws_size,
                              hipStream_t stream) {
    const float* q     = (const float*)d_in[0];
    const float* k     = (const float*)d_in[1];
    const float* v     = (const float*)d_in[2];
    const float* bias  = (const float*)d_in[3];
    const float* Wq    = (const float*)d_in[4];
    const float* Wk    = (const float*)d_in[5];
    const float* Wv    = (const float*)d_in[6];
    const float* Wo    = (const float*)d_in[7];
    const float* bo    = (const float*)d_in[8];
    const float* gamma = (const float*)d_in[9];
    const float* beta  = (const float*)d_in[10];
    const float* rmean = (const float*)d_in[11];
    const float* rvar  = (const float*)d_in[12];

    float* ws  = (float*)d_ws;
    float* out = (float*)d_out;

    // zero the barrier counters (graph-capture-legal; deterministic per call)
    hipMemsetAsync((char*)d_ws + CNT_OFF, 0, 64, stream);

    fused_kernel<<<dim3(256), dim3(1024), 0, stream>>>(
        q, k, v, bias, Wq, Wk, Wv, Wo, bo, gamma, beta, rmean, rvar, ws, out);
}

// Round 19
// 261.289 us; speedup vs baseline: 2.6464x; 2.6464x over previous
//
#include <hip/hip_runtime.h>
#include <hip/hip_cooperative_groups.h>

#define HID 256
#define NSEQ 1024
#define NH 16
#define DH 4
#define NB 4
#define SCALEF 0.5f
#define HEADSZ (NB * NH * NSEQ * DH)   // 262144 floats per projection buffer

typedef float f4 __attribute__((ext_vector_type(4)));

__device__ __forceinline__ float rfl(float x) {
    return __builtin_bit_cast(float,
        __builtin_amdgcn_readfirstlane(__builtin_bit_cast(int, x)));
}

#define LOG2E 1.44269504f
#define EOFF  (-16.f * LOG2E)

// ---------------------------------------------------------------------------
// Cooperative fusion, occupancy-preserving: 512 blocks x 512 threads =
// 2 blocks/CU x 8 waves = 16 waves/CU during attn — exactly R17's attn
// occupancy (R14's 250us coop failure was 8 waves/CU + nontemporal bias
// loads, both self-inflicted). Plain bias loads keep L3 allocation (R14/R18:
// FETCH ~148MB < 256MB bias -> L3 retains ~40% across replays).
// P1 proj: 96 blocks x 2 sub-units (R17 proj body).       grid.sync
// P2 attn: block=(b,h,seg of 128 rows), R17 body verbatim. grid.sync
// P3 out:  512 blocks x 2 sub-units (R13/R14-validated mapping).
// phase>=0 fallback: 3 normal launches of the same kernel (~R17 parity).
// ---------------------------------------------------------------------------
__global__ __launch_bounds__(512, 4) void fused_kernel(
    const float* __restrict__ q, const float* __restrict__ k,
    const float* __restrict__ v, const float* __restrict__ bias,
    const float* __restrict__ Wq, const float* __restrict__ Wk,
    const float* __restrict__ Wv, const float* __restrict__ Wo,
    const float* __restrict__ bo, const float* __restrict__ gamma,
    const float* __restrict__ beta, const float* __restrict__ rmean,
    const float* __restrict__ rvar, float* ws, float* out, int phase)
{
    __shared__ float smem[8192];               // 32 KB, reused per phase
    const int tid  = threadIdx.x;
    const int blk  = blockIdx.x;
    const bool coop = (phase < 0);
    float* x2 = ws + (size_t)3 * HEADSZ;

    // ---------------- P1: projections (96 blocks x 2 units) ----------------
    if ((coop || phase == 0) && blk < 96) {
        const int s    = tid >> 8;             // sub-unit 0..1
        const int stid = tid & 255;
        const int unit = blk * 2 + s;          // 192 proj units
        const int pos0 = (unit & 15) * 64;
        const int p    = (unit >> 4) % 3;
        const int b    = unit / 48;
        const float* in = (p == 0) ? q : (p == 1) ? k : v;
        const float* W  = (p == 0) ? Wq : (p == 1) ? Wk : Wv;
        float* dst = ws + (size_t)p * HEADSZ;

        float (*lds_in)[64] = (float(*)[64])(smem + s * 4096);  // 16KB each
        const int pos_l = stid & 63;
        int cb = __builtin_amdgcn_readfirstlane(stid >> 6);
        const int row_l = stid >> 4;
        const int col4  = stid & 15;
        const float* inb = in + (size_t)b * HID * NSEQ + pos0;

        float acc[16];
#pragma unroll
        for (int j = 0; j < 16; ++j) acc[j] = 0.f;

        f4 vbuf[4];
#pragma unroll
        for (int t = 0; t < 4; ++t)
            vbuf[t] = *(const f4*)(inb + (size_t)(row_l + 16 * t) * NSEQ + col4 * 4);

        for (int c = 0; c < 4; ++c) {
#pragma unroll
            for (int t = 0; t < 4; ++t)
                *(f4*)&lds_in[row_l + 16 * t][col4 * 4] = vbuf[t];
            __syncthreads();
            if (c < 3) {
#pragma unroll
                for (int t = 0; t < 4; ++t)
                    vbuf[t] = *(const f4*)(inb +
                        (size_t)((c + 1) * 64 + row_l + 16 * t) * NSEQ + col4 * 4);
            }
#pragma unroll
            for (int i8 = 0; i8 < 64; i8 += 8) {
                float x[8];
#pragma unroll
                for (int j = 0; j < 8; ++j) x[j] = lds_in[i8 + j][pos_l];
#pragma unroll
                for (int kk = 0; kk < 16; ++kk) {
                    const float* wr = W + (cb * 16 + kk) * HID + c * 64 + i8;
#pragma unroll
                    for (int j = 0; j < 8; ++j)
                        acc[kk] = fmaf(wr[j], x[j], acc[kk]);
                }
            }
            __syncthreads();
        }

        const int pos_g = pos0 + pos_l;
        const int hh    = pos_g & 15;
        const int nsub  = pos_g >> 4;
#pragma unroll
        for (int kk = 0; kk < 16; ++kk) {
            int c = cb * 16 + kk;
            int d = c >> 4;
            int n = (c & 15) * 64 + nsub;
            dst[(((size_t)b * NH + hh) * NSEQ + n) * DH + d] = acc[kk];
        }
    }

    if (coop) cooperative_groups::this_grid().sync();

    // ---------------- P2: attention (block = b, h, 128-row segment) -------
    if (coop || phase == 1) {
        const int lane = tid & 63;
        const int wave = tid >> 6;             // 0..7
        const int b    = blk >> 7;
        const int h    = (blk >> 3) & 15;
        const int seg  = blk & 7;
        const int headbase = (b * NH + h) * NSEQ;
        const int mb = lane * 4;

        const float4* Qh = (const float4*)(ws);
        const float4* Kh = (const float4*)(ws + (size_t)1 * HEADSZ);
        const float4* Vh = (const float4*)(ws + (size_t)2 * HEADSZ);

        float4* ldsK = (float4*)smem;          // 16 KB
        float4* ldsV = ldsK + NSEQ;            // 16 KB

        __syncthreads();                       // smem handoff
#pragma unroll
        for (int t = 0; t < 2; ++t) {
            ldsK[tid + 512 * t] = Kh[headbase + tid + 512 * t];
            ldsV[tid + 512 * t] = Vh[headbase + tid + 512 * t];
        }
        __syncthreads();

#pragma unroll 1
        for (int g = 0; g < 4; ++g) {          // 4 groups x 4 rows = 16/wave
            const int n0 = seg * 128 + wave * 16 + g * 4;

            float qx[4], qy[4], qz[4], qw[4];
#pragma unroll
            for (int r = 0; r < 4; ++r) {
                float4 t = Qh[headbase + n0 + r];
                qx[r] = rfl(t.x); qy[r] = rfl(t.y);
                qz[r] = rfl(t.z); qw[r] = rfl(t.w);
            }

            float sum[4];
            float o[4][4];
#pragma unroll
            for (int r = 0; r < 4; ++r) {
                sum[r] = 0.f;
                o[r][0] = o[r][1] = o[r][2] = o[r][3] = 0.f;
            }

            const float* bwave = bias + ((size_t)headbase + n0) * NSEQ + mb;

#pragma unroll 1
            for (int c = 0; c < 4; ++c) {
                float4 kb[4], vb[4];
#pragma unroll
                for (int i = 0; i < 4; ++i) {
                    kb[i] = ldsK[c * 256 + mb + i];
                    vb[i] = ldsV[c * 256 + mb + i];
                }
#pragma unroll
                for (int r = 0; r < 4; ++r) {
                    f4 bb = *(const f4*)(bwave + (size_t)r * NSEQ + c * 256);
#pragma unroll
                    for (int i = 0; i < 4; ++i) {
                        float dot = qx[r] * kb[i].x + qy[r] * kb[i].y +
                                    qz[r] * kb[i].z + qw[r] * kb[i].w;
                        float s = fmaf(dot, SCALEF, bb[i]);
                        float e = exp2f(fmaf(s, LOG2E, EOFF));   // exp(s-16)
                        sum[r] += e;
                        o[r][0] = fmaf(e, vb[i].x, o[r][0]);
                        o[r][1] = fmaf(e, vb[i].y, o[r][1]);
                        o[r][2] = fmaf(e, vb[i].z, o[r][2]);
                        o[r][3] = fmaf(e, vb[i].w, o[r][3]);
                    }
                }
            }

#pragma unroll
            for (int r = 0; r < 4; ++r) {
                float s = sum[r], a0 = o[r][0], a1 = o[r][1],
                      a2 = o[r][2], a3 = o[r][3];
#pragma unroll
                for (int st = 1; st < 64; st <<= 1) {
                    s  += __shfl_xor(s,  st, 64);
                    a0 += __shfl_xor(a0, st, 64);
                    a1 += __shfl_xor(a1, st, 64);
                    a2 += __shfl_xor(a2, st, 64);
                    a3 += __shfl_xor(a3, st, 64);
                }
                float val = (lane == 0) ? a0 : (lane == 1) ? a1
                          : (lane == 2) ? a2 : a3;
                if (lane < 4)
                    x2[((size_t)b * (NH * DH) + h * DH + lane) * NSEQ + n0 + r] =
                        val / s;
            }
        }
    }

    if (coop) cooperative_groups::this_grid().sync();

    // ---------------- P3: out-proj + BN + LeakyReLU (512 x 2 units) -------
    if (coop || phase == 2) {
        const int s    = tid >> 8;
        const int stid = tid & 255;
        const int u    = blk * 2 + s;          // 1024 units
        const int b      = u >> 8;
        const int r      = u & 255;
        const int chquad = r >> 2;
        const int posq   = r & 3;
        const int oc     = chquad * 4 + (stid >> 6);
        const int pos    = posq * 256 + (stid & 63) * 4;

        const float* xb = x2 + (size_t)b * (NH * DH) * NSEQ;
        f4 acc = (f4)(0.f);
#pragma unroll 16
        for (int c = 0; c < NH * DH; ++c) {
            f4 x = *(const f4*)(xb + (size_t)c * NSEQ + pos);
            acc += Wo[oc * (NH * DH) + c] * x;
        }
        float scale = gamma[oc] * rsqrtf(rvar[oc] + 1e-5f);
        f4 y = (acc + (bo[oc] - rmean[oc])) * scale + beta[oc];
        f4 res;
#pragma unroll
        for (int d = 0; d < 4; ++d) {
            float yy = y[d];
            res[d] = (yy > 0.f) ? yy : 0.2f * yy;
        }
        *(f4*)(out + ((size_t)b * HID + oc) * NSEQ + pos) = res;
    }
}

extern "C" void kernel_launch(void* const* d_in, const int* in_sizes, int n_in,
                              void* d_out, int out_size, void* d_ws, size_t ws_size,
                              hipStream_t stream) {
    const float* q     = (const float*)d_in[0];
    const float* k     = (const float*)d_in[1];
    const float* v     = (const float*)d_in[2];
    const float* bias  = (const float*)d_in[3];
    const float* Wq    = (const float*)d_in[4];
    const float* Wk    = (const float*)d_in[5];
    const float* Wv    = (const float*)d_in[6];
    const float* Wo    = (const float*)d_in[7];
    const float* bo    = (const float*)d_in[8];
    const float* gamma = (const float*)d_in[9];
    const float* beta  = (const float*)d_in[10];
    const float* rmean = (const float*)d_in[11];
    const float* rvar  = (const float*)d_in[12];

    float* ws  = (float*)d_ws;
    float* out = (float*)d_out;
    int phase = -1;

    void* args[] = {
        (void*)&q, (void*)&k, (void*)&v, (void*)&bias,
        (void*)&Wq, (void*)&Wk, (void*)&Wv, (void*)&Wo,
        (void*)&bo, (void*)&gamma, (void*)&beta, (void*)&rmean,
        (void*)&rvar, (void*)&ws, (void*)&out, (void*)&phase
    };
    hipError_t e = hipLaunchCooperativeKernel((void*)fused_kernel, dim3(512),
                                              dim3(512), args, 0, stream);
    if (e != hipSuccess) {
        (void)hipGetLastError();               // clear sticky error
        fused_kernel<<<dim3(512), dim3(512), 0, stream>>>(
            q, k, v, bias, Wq, Wk, Wv, Wo, bo, gamma, beta, rmean, rvar,
            ws, out, 0);
        fused_kernel<<<dim3(512), dim3(512), 0, stream>>>(
            q, k, v, bias, Wq, Wk, Wv, Wo, bo, gamma, beta, rmean, rvar,
            ws, out, 1);
        fused_kernel<<<dim3(512), dim3(512), 0, stream>>>(
            q, k, v, bias, Wq, Wk, Wv, Wo, bo, gamma, beta, rmean, rvar,
            ws, out, 2);
    }
}

// Round 21
// 121.176 us; speedup vs baseline: 5.7064x; 2.1563x over previous
//
#include <hip/hip_runtime.h>

#define HID 256
#define NSEQ 1024
#define NH 16
#define DH 4
#define NB 4
#define SCALEF 0.5f
#define HEADSZ (NB * NH * NSEQ * DH)   // 262144 floats per projection buffer

typedef float f4 __attribute__((ext_vector_type(4)));

__device__ __forceinline__ float rfl(float x) {
    return __builtin_bit_cast(float,
        __builtin_amdgcn_readfirstlane(__builtin_bit_cast(int, x)));
}

#define LOG2E 1.44269504f
#define EOFF  (-16.f * LOG2E)

// ---------------------------------------------------------------------------
// Kernel 1: 1x1-conv projections (unchanged, writes [B][H][N][D] view).
// ---------------------------------------------------------------------------
__global__ __launch_bounds__(256) void proj_kernel(
    const float* __restrict__ q, const float* __restrict__ k,
    const float* __restrict__ v, const float* __restrict__ Wq,
    const float* __restrict__ Wk, const float* __restrict__ Wv,
    float* __restrict__ ws)
{
    const int tid   = threadIdx.x;
    const int pos_l = tid & 63;
    int cb = __builtin_amdgcn_readfirstlane(tid >> 6);
    const int p    = blockIdx.y;
    const int b    = blockIdx.z;
    const int pos0 = blockIdx.x * 64;

    const float* in = (p == 0) ? q : (p == 1) ? k : v;
    const float* W  = (p == 0) ? Wq : (p == 1) ? Wk : Wv;
    float* dst = ws + (size_t)p * HEADSZ;

    __shared__ float lds_in[64][64];

    const int row_l = tid >> 4;
    const int col4  = tid & 15;
    const float* inb = in + (size_t)b * HID * NSEQ + pos0;

    float acc[16];
#pragma unroll
    for (int j = 0; j < 16; ++j) acc[j] = 0.f;

    f4 vbuf[4];
#pragma unroll
    for (int t = 0; t < 4; ++t)
        vbuf[t] = *(const f4*)(inb + (size_t)(row_l + 16 * t) * NSEQ + col4 * 4);

    for (int c = 0; c < 4; ++c) {
#pragma unroll
        for (int t = 0; t < 4; ++t)
            *(f4*)&lds_in[row_l + 16 * t][col4 * 4] = vbuf[t];
        __syncthreads();
        if (c < 3) {
#pragma unroll
            for (int t = 0; t < 4; ++t)
                vbuf[t] = *(const f4*)(inb +
                    (size_t)((c + 1) * 64 + row_l + 16 * t) * NSEQ + col4 * 4);
        }
#pragma unroll
        for (int i8 = 0; i8 < 64; i8 += 8) {
            float x[8];
#pragma unroll
            for (int j = 0; j < 8; ++j) x[j] = lds_in[i8 + j][pos_l];
#pragma unroll
            for (int kk = 0; kk < 16; ++kk) {
                const float* wr = W + (cb * 16 + kk) * HID + c * 64 + i8;
#pragma unroll
                for (int j = 0; j < 8; ++j)
                    acc[kk] = fmaf(wr[j], x[j], acc[kk]);
            }
        }
        __syncthreads();
    }

    const int pos_g = pos0 + pos_l;
    const int h     = pos_g & 15;
    const int nsub  = pos_g >> 4;
#pragma unroll
    for (int kk = 0; kk < 16; ++kk) {
        int c = cb * 16 + kk;
        int d = c >> 4;
        int n = (c & 15) * 64 + nsub;
        dst[(((size_t)b * NH + h) * NSEQ + n) * DH + d] = acc[kk];
    }
}

// ---------------------------------------------------------------------------
// Kernel 2: attention + out-proj, BLOCK-LOCAL fusion (no cross-block sync).
// Block = (seg of 8 rows, b); 512 threads = 8 waves; wave w handles heads
// w*2, w*2+1 SEQUENTIALLY with the R12-proven 8-row register profile; lanes
// split keys 64-way (mb = lane*4). K/V read directly from global (2MB
// working set, L2/L3-resident, 8x register reuse) — no LDS staging, so the
// 3.1M ds bank conflicts vanish. x2 for this (b,seg) is written to a 2KB
// LDS tile; after one __syncthreads the same block runs out-proj+BN+LReLU
// (thread = (oc, row-half), LDS broadcast reads, coalesced f4 stores).
// Eliminates: one node gap, the out kernel, the x2 global round-trip.
// ---------------------------------------------------------------------------
__global__ __launch_bounds__(512, 4) void attn_out_kernel(
    const float* __restrict__ bias, const float* __restrict__ ws,
    const float* __restrict__ Wo, const float* __restrict__ bo,
    const float* __restrict__ gamma, const float* __restrict__ beta,
    const float* __restrict__ rmean, const float* __restrict__ rvar,
    float* __restrict__ out)
{
    const int tid  = threadIdx.x;
    const int lane = tid & 63;
    const int wave = tid >> 6;                  // 0..7
    const int seg  = blockIdx.x;                // 128 segments of 8 rows
    const int b    = blockIdx.y;
    const int n0   = seg * 8;
    const int mb   = lane * 4;

    const float4* Qh = (const float4*)(ws);
    const float4* Kh = (const float4*)(ws + (size_t)1 * HEADSZ);
    const float4* Vh = (const float4*)(ws + (size_t)2 * HEADSZ);

    __shared__ float x2l[64][9];                // [channel][row(+pad)]

#pragma unroll 1
    for (int h2 = 0; h2 < 2; ++h2) {
        const int h = wave * 2 + h2;
        const int headbase = (b * NH + h) * NSEQ;

        // Q -> SGPRs (lane-uniform)
        float qx[8], qy[8], qz[8], qw[8];
#pragma unroll
        for (int r = 0; r < 8; ++r) {
            float4 t = Qh[headbase + n0 + r];
            qx[r] = rfl(t.x); qy[r] = rfl(t.y);
            qz[r] = rfl(t.z); qw[r] = rfl(t.w);
        }

        float sum[8];
        float o[8][4];
#pragma unroll
        for (int r = 0; r < 8; ++r) {
            sum[r] = 0.f;
            o[r][0] = o[r][1] = o[r][2] = o[r][3] = 0.f;
        }

        const float* bwave = bias + ((size_t)headbase + n0) * NSEQ + mb;

#pragma unroll 1
        for (int c = 0; c < 4; ++c) {           // 4 chunks x 256 keys
            const int kv = headbase + c * 256 + mb;
            float4 kb[4], vb[4];
#pragma unroll
            for (int i = 0; i < 4; ++i) {
                kb[i] = Kh[kv + i];             // global: L2/L3-resident
                vb[i] = Vh[kv + i];
            }
#pragma unroll
            for (int r = 0; r < 8; ++r) {
                f4 bb = *(const f4*)(bwave + (size_t)r * NSEQ + c * 256);
#pragma unroll
                for (int i = 0; i < 4; ++i) {
                    float dot = qx[r] * kb[i].x + qy[r] * kb[i].y +
                                qz[r] * kb[i].z + qw[r] * kb[i].w;
                    float s = fmaf(dot, SCALEF, bb[i]);
                    float e = exp2f(fmaf(s, LOG2E, EOFF));   // exp(s-16)
                    sum[r] += e;
                    o[r][0] = fmaf(e, vb[i].x, o[r][0]);
                    o[r][1] = fmaf(e, vb[i].y, o[r][1]);
                    o[r][2] = fmaf(e, vb[i].z, o[r][2]);
                    o[r][3] = fmaf(e, vb[i].w, o[r][3]);
                }
            }
        }

        // butterfly per row; lanes 0..3 write x2 into the LDS tile
#pragma unroll
        for (int r = 0; r < 8; ++r) {
            float s = sum[r], a0 = o[r][0], a1 = o[r][1],
                  a2 = o[r][2], a3 = o[r][3];
#pragma unroll
            for (int st = 1; st < 64; st <<= 1) {
                s  += __shfl_xor(s,  st, 64);
                a0 += __shfl_xor(a0, st, 64);
                a1 += __shfl_xor(a1, st, 64);
                a2 += __shfl_xor(a2, st, 64);
                a3 += __shfl_xor(a3, st, 64);
            }
            float val = (lane == 0) ? a0 : (lane == 1) ? a1
                      : (lane == 2) ? a2 : a3;
            if (lane < 4)
                x2l[h * DH + lane][r] = val / s;
        }
    }

    __syncthreads();                            // x2 tile complete (block-local)

    // ---------------- out-proj + BN + LeakyReLU (in-block) ----------------
    {
        const int oc = tid & 255;
        const int rh = tid >> 8;                // row-half: rows rh*4..rh*4+3
        const float* wr = Wo + oc * (NH * DH);

        f4 acc = (f4)(0.f);
#pragma unroll
        for (int c = 0; c < NH * DH; ++c) {
            float wv = wr[c];
            acc[0] = fmaf(wv, x2l[c][rh * 4 + 0], acc[0]);
            acc[1] = fmaf(wv, x2l[c][rh * 4 + 1], acc[1]);
            acc[2] = fmaf(wv, x2l[c][rh * 4 + 2], acc[2]);
            acc[3] = fmaf(wv, x2l[c][rh * 4 + 3], acc[3]);
        }
        float scale = gamma[oc] * rsqrtf(rvar[oc] + 1e-5f);
        f4 y = (acc + (bo[oc] - rmean[oc])) * scale + beta[oc];
        f4 res;
#pragma unroll
        for (int d = 0; d < 4; ++d) {
            float yy = y[d];
            res[d] = (yy > 0.f) ? yy : 0.2f * yy;
        }
        *(f4*)(out + ((size_t)b * HID + oc) * NSEQ + n0 + rh * 4) = res;
    }
}

extern "C" void kernel_launch(void* const* d_in, const int* in_sizes, int n_in,
                              void* d_out, int out_size, void* d_ws, size_t ws_size,
                              hipStream_t stream) {
    const float* q     = (const float*)d_in[0];
    const float* k     = (const float*)d_in[1];
    const float* v     = (const float*)d_in[2];
    const float* bias  = (const float*)d_in[3];
    const float* Wq    = (const float*)d_in[4];
    const float* Wk    = (const float*)d_in[5];
    const float* Wv    = (const float*)d_in[6];
    const float* Wo    = (const float*)d_in[7];
    const float* bo    = (const float*)d_in[8];
    const float* gamma = (const float*)d_in[9];
    const float* beta  = (const float*)d_in[10];
    const float* rmean = (const float*)d_in[11];
    const float* rvar  = (const float*)d_in[12];

    float* ws  = (float*)d_ws;
    float* out = (float*)d_out;

    proj_kernel<<<dim3(NSEQ / 64, 3, NB), 256, 0, stream>>>(q, k, v, Wq, Wk, Wv, ws);
    attn_out_kernel<<<dim3(NSEQ / 8, NB), 512, 0, stream>>>(
        bias, ws, Wo, bo, gamma, beta, rmean, rvar, out);
}